// Round 5
// baseline (1532.638 us; speedup 1.0000x reference)
//
#include <hip/hip_runtime.h>
#include <hip/hip_bf16.h>

#define D_MODEL 4096
#define D_FF    11008
#define NTOK    4096   // 2 * 2048 tokens

typedef unsigned int u32;
typedef unsigned short u16;
using f32x4   = __attribute__((ext_vector_type(4))) float;
using bf16x8  = __attribute__((ext_vector_type(8))) short;
using ushort8 = __attribute__((ext_vector_type(8))) unsigned short;
using int4v   = __attribute__((ext_vector_type(4))) int;
using float4v = __attribute__((ext_vector_type(4))) float;

__device__ __forceinline__ u16 bf16_rn(float f) {
    u32 u = __builtin_bit_cast(u32, f);
    u += 0x7FFFu + ((u >> 16) & 1u);
    return (u16)(u >> 16);
}
__device__ __forceinline__ u16 bf16_from_int(int v) {
    float f = (float)v;   // exact for |v| <= 127
    return (u16)(__builtin_bit_cast(u32, f) >> 16);
}
__device__ __forceinline__ float bf16_to_f(u16 b) {
    u32 u = (u32)b << 16;
    return __builtin_bit_cast(float, u);
}

// ---------------- x fp32 -> bf16 ----------------
__global__ void k_cvt_x(const float* __restrict__ x, u16* __restrict__ xb) {
    int i = (blockIdx.x * 256 + threadIdx.x) * 8;
    float4v a = *(const float4v*)(x + i);
    float4v b = *(const float4v*)(x + i + 4);
    ushort8 o;
    o[0] = bf16_rn(a[0]); o[1] = bf16_rn(a[1]); o[2] = bf16_rn(a[2]); o[3] = bf16_rn(a[3]);
    o[4] = bf16_rn(b[0]); o[5] = bf16_rn(b[1]); o[6] = bf16_rn(b[2]); o[7] = bf16_rn(b[3]);
    *(ushort8*)(xb + i) = o;
}

// ---------------- weight int32 -> bf16 ----------------
__global__ void k_cvt_w(const int* __restrict__ w, u16* __restrict__ wb, int n) {
    int i = (blockIdx.x * 256 + threadIdx.x) * 8;
    if (i >= n) return;
    int4v a = *(const int4v*)(w + i);
    int4v b = *(const int4v*)(w + i + 4);
    ushort8 o;
    o[0] = bf16_from_int(a[0]); o[1] = bf16_from_int(a[1]);
    o[2] = bf16_from_int(a[2]); o[3] = bf16_from_int(a[3]);
    o[4] = bf16_from_int(b[0]); o[5] = bf16_from_int(b[1]);
    o[6] = bf16_from_int(b[2]); o[7] = bf16_from_int(b[3]);
    *(ushort8*)(wb + i) = o;
}

// =====================================================================
// 256x256 GEMM, 4 quadrant-phases/K-tile, REG-STAGED (no global_load_lds):
// global loads -> VGPR (tile t: P3/P4, for tile t+2), ds_write_b128 one
// tile later (t+1: P1/P2) into the opposite buffer. Tile t reads buf(t&1)
// and writes buf(~t&1) only -> no LDS-DMA, no vmem outstanding semantics
// at barriers; compiler inserts precise counted vmcnt before each
// ds_write (register dependency). C = A[M][K]*(B[N][K])^T, bf16 K-major,
// 8 waves (2Mx4N), BK=64, 128 KiB LDS, XOR-granule swizzle.
// EPI: 0 = obf = bf16(acc*scale)                      (gate)
//      1 = obf = bf16(silu(g)*acc*scale), g from obf  (up + fuse)
//      2 = of32 = acc*scale                           (down)
// =====================================================================

#define DSR(dst, addr, IMM)                                                   \
  asm volatile("ds_read_b128 %0, %1 offset:%c2"                               \
               : "=v"(dst) : "v"(addr), "i"(IMM))
#define DSW(addr, IMM, val)                                                   \
  asm volatile("ds_write_b128 %0, %1 offset:%c2"                              \
               :: "v"(addr), "v"(val), "i"(IMM))

// A-half byte layout: buf*65536 + half*16384, row stride 128B, m-stride 2048B
#define READA(AA, BUF, MH) {                                                  \
  DSR(AA[0][0], adA##BUF##g0, (MH)*16384 + 0);                                \
  DSR(AA[0][1], adA##BUF##g1, (MH)*16384 + 0);                                \
  DSR(AA[1][0], adA##BUF##g0, (MH)*16384 + 2048);                             \
  DSR(AA[1][1], adA##BUF##g1, (MH)*16384 + 2048);                             \
  DSR(AA[2][0], adA##BUF##g0, (MH)*16384 + 4096);                             \
  DSR(AA[2][1], adA##BUF##g1, (MH)*16384 + 4096);                             \
  DSR(AA[3][0], adA##BUF##g0, (MH)*16384 + 6144);                             \
  DSR(AA[3][1], adA##BUF##g1, (MH)*16384 + 6144); }

#define READB(BB, BUF, NH) {                                                  \
  DSR(BB[0][0], adB##BUF##g0, (NH)*16384 + 0);                                \
  DSR(BB[0][1], adB##BUF##g1, (NH)*16384 + 0);                                \
  DSR(BB[1][0], adB##BUF##g0, (NH)*16384 + 2048);                             \
  DSR(BB[1][1], adB##BUF##g1, (NH)*16384 + 2048); }

#define MFMA16(MH, NH, AA, BB)                                                \
  _Pragma("unroll") for (int mm = 0; mm < 4; ++mm)                            \
  _Pragma("unroll") for (int nn = 0; nn < 2; ++nn)                            \
  _Pragma("unroll") for (int kk = 0; kk < 2; ++kk)                            \
    acc[(MH)*4+mm][(NH)*2+nn] = __builtin_amdgcn_mfma_f32_16x16x32_bf16(      \
        AA[mm][kk], BB[nn][kk], acc[(MH)*4+mm][(NH)*2+nn], 0, 0, 0);

#define LOAD_A(K0) {                                                          \
  const u16* _p = A + a_sbase + (size_t)(K0);                                 \
  stA0 = *(const ushort8*)(_p);                                               \
  stA1 = *(const ushort8*)(_p + (size_t)64*K);                                \
  stA2 = *(const ushort8*)(_p + (size_t)128*K);                               \
  stA3 = *(const ushort8*)(_p + (size_t)192*K); }

#define LOAD_B(K0) {                                                          \
  const u16* _p = B + b_sbase + (size_t)(K0);                                 \
  stB0 = *(const ushort8*)(_p);                                               \
  stB1 = *(const ushort8*)(_p + (size_t)64*K);                                \
  stB2 = *(const ushort8*)(_p + (size_t)128*K);                               \
  stB3 = *(const ushort8*)(_p + (size_t)192*K); }

#define WRITE_H0(BUF) {                                                       \
  DSW(wdA##BUF, 0, stA0);      DSW(wdA##BUF, 8192, stA1);                     \
  DSW(wdB##BUF, 0, stB0);      DSW(wdB##BUF, 8192, stB1); }

#define WRITE_H1(BUF) {                                                       \
  DSW(wdA##BUF, 16384, stA2);  DSW(wdA##BUF, 24576, stA3);                    \
  DSW(wdB##BUF, 16384, stB2);  DSW(wdB##BUF, 24576, stB3); }

#define BAR   __builtin_amdgcn_s_barrier()
#define SB0   __builtin_amdgcn_sched_barrier(0)
#define PRIO1 __builtin_amdgcn_s_setprio(1)
#define PRIO0 __builtin_amdgcn_s_setprio(0)
#define LGKM(N) asm volatile("s_waitcnt lgkmcnt(" #N ")" ::: "memory")

#define TILE(CUR, NXT, T) {                                                   \
  /* P1: Q1(a0,b0); ds_write staged half0 -> NXT (data loaded tile T-1) */    \
  READA(a0, CUR, 0); READB(b0, CUR, 0);                                       \
  if ((T)+1 < nt) WRITE_H0(NXT);                                              \
  BAR; LGKM(0); SB0; PRIO1; MFMA16(0, 0, a0, b0); PRIO0; BAR;                 \
  /* P2: Q2(a0,b1); ds_write staged half1 -> NXT */                           \
  READB(b1, CUR, 1);                                                          \
  if ((T)+1 < nt) WRITE_H1(NXT);                                              \
  BAR; LGKM(0); SB0; PRIO1; MFMA16(0, 1, a0, b1); PRIO0; BAR;                 \
  /* P3: Q3(a1,b1); issue A-loads for tile T+2 */                             \
  READA(a1, CUR, 1);                                                          \
  if ((T)+2 < nt) LOAD_A(((T)+2) << 6);                                       \
  BAR; LGKM(0); SB0; PRIO1; MFMA16(1, 1, a1, b1); PRIO0; BAR;                 \
  /* P4: Q4(a1,b0) from held regs; issue B-loads for tile T+2 */              \
  if ((T)+2 < nt) LOAD_B(((T)+2) << 6);                                       \
  SB0; PRIO1; MFMA16(1, 0, a1, b0); PRIO0; BAR; }

template<int EPI>
__global__ __launch_bounds__(512, 2) void k_gemm256(
    const u16* __restrict__ A, const u16* __restrict__ B,
    const float* __restrict__ scale,
    u16* __restrict__ obf, float* __restrict__ of32,
    int K, int NBN, int ldc)
{
    __shared__ __align__(16) u16 lds[65536];   // 128 KiB

    const int tid  = threadIdx.x;
    const int lane = tid & 63;
    const int wave = tid >> 6;          // 0..7
    const int wm   = wave >> 2;         // 0..1
    const int wn   = wave & 3;          // 0..3

    // XCD-aware bijective swizzle (m204)
    const int nwg  = 16 * NBN;
    const int orig = blockIdx.x;
    const int qq   = nwg >> 3, rr = nwg & 7;
    const int xcd  = orig & 7;
    const int swz  = (xcd < rr ? xcd*(qq+1) : rr*(qq+1) + (xcd-rr)*qq) + (orig >> 3);
    const int bm   = swz & 15;          // M blocks = 4096/256 = 16
    const int bn   = swz >> 4;

    // fragment-read per-thread constants (byte offsets)
    const int r    = lane & 15;
    const int sQ   = lane >> 4;         // 0..3
    const int x7   = r & 7;
    const int g0B  = ((sQ ^ x7) * 8) * 2;         // kk=0 granule, bytes
    const int g1B  = (((4 | sQ) ^ x7) * 8) * 2;   // kk=1 granule, bytes
    const int aoffB = (wm*64 + r) * 128;
    const int boffB = (wn*32 + r) * 128;

    const u32 lbase = (u32)(uintptr_t)(__attribute__((address_space(3))) u16*)&lds[0];
    const u32 adA0g0 = lbase + aoffB + g0B;
    const u32 adA0g1 = lbase + aoffB + g1B;
    const u32 adA1g0 = adA0g0 + 65536;
    const u32 adA1g1 = adA0g1 + 65536;
    const u32 adB0g0 = lbase + 32768 + boffB + g0B;
    const u32 adB0g1 = lbase + 32768 + boffB + g1B;
    const u32 adB1g0 = adB0g0 + 65536;
    const u32 adB1g1 = adB0g1 + 65536;

    // staging constants: per-lane global source (pre-swizzled) and LDS dest
    const int lrow = lane >> 3;                       // 0..7
    const int goff = ((lane & 7) ^ lrow) * 8;         // elems within 64-col row
    const size_t a_sbase = (size_t)(bm*256 + wave*8 + lrow) * K + goff;
    const size_t b_sbase = (size_t)(bn*256 + wave*8 + lrow) * K + goff;
    const u32 wdA0 = lbase + wave*1024 + lane*16;     // bytes
    const u32 wdA1 = wdA0 + 65536;
    const u32 wdB0 = lbase + 32768 + wave*1024 + lane*16;
    const u32 wdB1 = wdB0 + 65536;

    f32x4 acc[8][4];
#pragma unroll
    for (int m = 0; m < 8; ++m)
#pragma unroll
        for (int n = 0; n < 4; ++n) acc[m][n] = (f32x4){0.f, 0.f, 0.f, 0.f};

    const int nt = K >> 6;              // K/64: 64 (K=4096) or 172 (K=11008), even

    // ---- prologue: load tile0 -> regs -> buf0; load tile1 -> regs (held)
    ushort8 stA0, stA1, stA2, stA3, stB0, stB1, stB2, stB3;
    LOAD_A(0); LOAD_B(0);
    WRITE_H0(0); WRITE_H1(0);           // compiler inserts vmcnt before use
    LOAD_A(64); LOAD_B(64);             // tile1 set, written during t=0
    LGKM(0);
    BAR;

    bf16x8 a0[4][2], a1[4][2], b0[2][2], b1[2][2];

    for (int t = 0; t < nt; t += 2) {
        TILE(0, 1, t);
        TILE(1, 0, t + 1);
    }

    // ---- epilogue
#pragma unroll
    for (int n = 0; n < 4; ++n) {
        const int col = bn*256 + (n>>1)*128 + wn*32 + (n&1)*16 + r;
        const float sc = scale[col];
#pragma unroll
        for (int m = 0; m < 8; ++m) {
            const int row = bm*256 + (m>>2)*128 + wm*64 + (m&3)*16 + sQ*4;
#pragma unroll
            for (int q = 0; q < 4; ++q) {
                const float v = acc[m][n][q] * sc;
                const size_t idx = (size_t)(row + q) * ldc + col;
                if constexpr (EPI == 0) {
                    obf[idx] = bf16_rn(v);
                } else if constexpr (EPI == 1) {
                    const float g = bf16_to_f(obf[idx]);
                    const float s2 = g / (1.0f + __expf(-g));
                    obf[idx] = bf16_rn(s2 * v);
                } else {
                    of32[idx] = v;
                }
            }
        }
    }
}

extern "C" void kernel_launch(void* const* d_in, const int* in_sizes, int n_in,
                              void* d_out, int out_size, void* d_ws, size_t ws_size,
                              hipStream_t stream) {
    const float* x  = (const float*)d_in[0];
    const int*   gw = (const int*)d_in[1];
    const float* gs = (const float*)d_in[2];
    const int*   uw = (const int*)d_in[3];
    const float* us = (const float*)d_in[4];
    const int*   dw = (const int*)d_in[5];
    const float* ds = (const float*)d_in[6];
    float* out = (float*)d_out;

    const size_t XB = (size_t)NTOK * D_MODEL * 2;   // 33.5 MB  x bf16
    const size_t WB = (size_t)D_FF * D_MODEL * 2;   // 90.2 MB  weight bf16
    const size_t HB = WB;                           // 90.2 MB  g/h bf16
    if (ws_size < XB + WB + HB) return;             // loud failure (poisoned out)

    char* ws = (char*)d_ws;
    u16* xb   = (u16*)ws;
    u16* wb   = (u16*)(ws + XB);
    u16* gbuf = (u16*)(ws + XB + WB);

    const int wn_elems = D_FF * D_MODEL;            // 45,088,768
    const int wgrid = wn_elems / (8 * 256);

    k_cvt_x<<<(NTOK * D_MODEL) / (8 * 256), 256, 0, stream>>>(x, xb);

    // gate: g = bf16( (xb . gw^T) * gs )
    k_cvt_w<<<wgrid, 256, 0, stream>>>(gw, wb, wn_elems);
    k_gemm256<0><<<16 * (D_FF / 256), 512, 0, stream>>>(
        xb, wb, gs, gbuf, nullptr, D_MODEL, D_FF / 256, D_FF);

    // up + fuse: h = bf16( silu(g) * (xb . uw^T) * us )   (in-place into gbuf)
    k_cvt_w<<<wgrid, 256, 0, stream>>>(uw, wb, wn_elems);
    k_gemm256<1><<<16 * (D_FF / 256), 512, 0, stream>>>(
        xb, wb, us, gbuf, nullptr, D_MODEL, D_FF / 256, D_FF);

    // down: out = (h . dw^T) * ds   (fp32)
    k_cvt_w<<<wgrid, 256, 0, stream>>>(dw, wb, wn_elems);
    k_gemm256<2><<<16 * (D_MODEL / 256), 512, 0, stream>>>(
        gbuf, wb, ds, nullptr, out, D_FF, D_MODEL / 256, D_MODEL);
}

// Round 8
// 1258.415 us; speedup vs baseline: 1.2179x; 1.2179x over previous
//
#include <hip/hip_runtime.h>
#include <hip/hip_bf16.h>

#define D_MODEL 4096
#define D_FF    11008
#define NTOK    4096   // 2 * 2048 tokens

typedef unsigned int u32;
typedef unsigned short u16;
using f32x4   = __attribute__((ext_vector_type(4))) float;
using bf16x8  = __attribute__((ext_vector_type(8))) short;
using ushort8 = __attribute__((ext_vector_type(8))) unsigned short;
using int4v   = __attribute__((ext_vector_type(4))) int;
using float4v = __attribute__((ext_vector_type(4))) float;

__device__ __forceinline__ u16 bf16_rn(float f) {
    u32 u = __builtin_bit_cast(u32, f);
    u += 0x7FFFu + ((u >> 16) & 1u);
    return (u16)(u >> 16);
}
__device__ __forceinline__ u16 bf16_from_int(int v) {
    float f = (float)v;   // exact for |v| <= 127
    return (u16)(__builtin_bit_cast(u32, f) >> 16);
}
__device__ __forceinline__ float bf16_to_f(u16 b) {
    u32 u = (u32)b << 16;
    return __builtin_bit_cast(float, u);
}
__device__ __forceinline__ void gload16(const void* g, void* l) {
    __builtin_amdgcn_global_load_lds(
        (const __attribute__((address_space(1))) u32*)g,
        (__attribute__((address_space(3))) u32*)l, 16, 0, 0);
}

// ---------------- x fp32 -> bf16 ----------------
__global__ void k_cvt_x(const float* __restrict__ x, u16* __restrict__ xb) {
    int i = (blockIdx.x * 256 + threadIdx.x) * 8;
    float4v a = *(const float4v*)(x + i);
    float4v b = *(const float4v*)(x + i + 4);
    ushort8 o;
    o[0] = bf16_rn(a[0]); o[1] = bf16_rn(a[1]); o[2] = bf16_rn(a[2]); o[3] = bf16_rn(a[3]);
    o[4] = bf16_rn(b[0]); o[5] = bf16_rn(b[1]); o[6] = bf16_rn(b[2]); o[7] = bf16_rn(b[3]);
    *(ushort8*)(xb + i) = o;
}

// ---------------- weight int32 -> bf16 ----------------
__global__ void k_cvt_w(const int* __restrict__ w, u16* __restrict__ wb, int n) {
    int i = (blockIdx.x * 256 + threadIdx.x) * 8;
    if (i >= n) return;
    int4v a = *(const int4v*)(w + i);
    int4v b = *(const int4v*)(w + i + 4);
    ushort8 o;
    o[0] = bf16_from_int(a[0]); o[1] = bf16_from_int(a[1]);
    o[2] = bf16_from_int(a[2]); o[3] = bf16_from_int(a[3]);
    o[4] = bf16_from_int(b[0]); o[5] = bf16_from_int(b[1]);
    o[6] = bf16_from_int(b[2]); o[7] = bf16_from_int(b[3]);
    *(ushort8*)(wb + i) = o;
}

// =====================================================================
// 256x256 GEMM, 2 phases/K-tile (32 MFMA per barrier region).
// C = A[M][K] * (B[N][K])^T (both bf16, K-major). 8 waves (2M x 4N),
// BK=64, double-buffered 128 KiB LDS, XOR-granule swizzle, gload_lds
// staging (pre-swizzled source), counted vmcnt(6), setprio.
// WAR discipline: every LDS region overwrite is issued only after its
// readers' lgkmcnt(0) + barrier (>= 1 phase earlier):
//   Ph1 stages NXT.A.h1   (readers: a1 of T-1, drained T-1.Ph2)
//   Ph2 stages CUR.A.h0,B.h0,B.h1 (readers: Ph1's a0/b0/b1, drained Ph1)
// RAW: vmcnt(6) at Ph2 gates the entire next-tile buffer (oldest needed
// = A(T+1)h1 staged this Ph1; exactly 6 newer gloads follow it).
// EPI: 0 = obf = bf16(acc*scale)                      (gate)
//      1 = obf = bf16(silu(g)*acc*scale), g from obf  (up + fuse)
//      2 = of32 = acc*scale                           (down)
// =====================================================================

#define DSR(dst, addr, IMM)                                                   \
  asm volatile("ds_read_b128 %0, %1 offset:%c2"                               \
               : "=v"(dst) : "v"(addr), "i"(IMM))

// A-half byte layout: buf*65536 + half*16384, row stride 128B, m-stride 2048B
#define READA(AA, BUF, MH) {                                                  \
  DSR(AA[0][0], adA##BUF##g0, (MH)*16384 + 0);                                \
  DSR(AA[0][1], adA##BUF##g1, (MH)*16384 + 0);                                \
  DSR(AA[1][0], adA##BUF##g0, (MH)*16384 + 2048);                             \
  DSR(AA[1][1], adA##BUF##g1, (MH)*16384 + 2048);                             \
  DSR(AA[2][0], adA##BUF##g0, (MH)*16384 + 4096);                             \
  DSR(AA[2][1], adA##BUF##g1, (MH)*16384 + 4096);                             \
  DSR(AA[3][0], adA##BUF##g0, (MH)*16384 + 6144);                             \
  DSR(AA[3][1], adA##BUF##g1, (MH)*16384 + 6144); }

#define READB(BB, BUF, NH) {                                                  \
  DSR(BB[0][0], adB##BUF##g0, (NH)*16384 + 0);                                \
  DSR(BB[0][1], adB##BUF##g1, (NH)*16384 + 0);                                \
  DSR(BB[1][0], adB##BUF##g0, (NH)*16384 + 2048);                             \
  DSR(BB[1][1], adB##BUF##g1, (NH)*16384 + 2048); }

#define MFMA16(MH, NH, AA, BB)                                                \
  _Pragma("unroll") for (int mm = 0; mm < 4; ++mm)                            \
  _Pragma("unroll") for (int nn = 0; nn < 2; ++nn)                            \
  _Pragma("unroll") for (int kk = 0; kk < 2; ++kk)                            \
    acc[(MH)*4+mm][(NH)*2+nn] = __builtin_amdgcn_mfma_f32_16x16x32_bf16(      \
        AA[mm][kk], BB[nn][kk], acc[(MH)*4+mm][(NH)*2+nn], 0, 0, 0);

// LDS element offsets for staging (ushort units)
#define REGA(BUF, H) ((BUF)*32768 + (H)*8192)
#define REGB(BUF, H) ((BUF)*32768 + 16384 + (H)*8192)

#define STAGE_A(BUF, MH, K0) {                                                \
  const u16* _s = A + a_sbase + (size_t)(MH)*128*K + (K0);                    \
  gload16(_s,                &lds[REGA(BUF, MH) + wave*512]);                 \
  gload16(_s + (size_t)64*K, &lds[REGA(BUF, MH) + (8+wave)*512]); }

#define STAGE_B(BUF, NH, K0) {                                                \
  const u16* _s = B + b_sbase + (size_t)(NH)*128*K + (K0);                    \
  gload16(_s,                &lds[REGB(BUF, NH) + wave*512]);                 \
  gload16(_s + (size_t)64*K, &lds[REGB(BUF, NH) + (8+wave)*512]); }

#define BAR   __builtin_amdgcn_s_barrier()
#define SB0   __builtin_amdgcn_sched_barrier(0)
#define PRIO1 __builtin_amdgcn_s_setprio(1)
#define PRIO0 __builtin_amdgcn_s_setprio(0)
#define VMC(N)  asm volatile("s_waitcnt vmcnt(" #N ")" ::: "memory")
#define LGKM(N) asm volatile("s_waitcnt lgkmcnt(" #N ")" ::: "memory")

#define TILE2(CUR, NXT, T) {                                                  \
  /* Ph1: read a0,b0,b1 of CUR; stage A(T+1)h1 -> NXT; MFMA Q1,Q2 */          \
  READA(a0, CUR, 0); READB(b0, CUR, 0); READB(b1, CUR, 1);                    \
  if ((T)+1 < nt) STAGE_A(NXT, 1, ((T)+1) << 6);                              \
  BAR; LGKM(0); SB0; PRIO1;                                                   \
  MFMA16(0, 0, a0, b0); MFMA16(0, 1, a0, b1);                                 \
  PRIO0; BAR;                                                                 \
  /* Ph2: read a1 of CUR; stage A(T+2)h0,B(T+2)h0,B(T+2)h1 -> CUR;   */       \
  /*      MFMA Q3,Q4; counted vmcnt gates next tile's buffer          */      \
  READA(a1, CUR, 1);                                                          \
  if ((T)+2 < nt) { STAGE_A(CUR, 0, ((T)+2) << 6);                            \
                    STAGE_B(CUR, 0, ((T)+2) << 6);                            \
                    STAGE_B(CUR, 1, ((T)+2) << 6); }                          \
  BAR; LGKM(0); SB0; PRIO1;                                                   \
  MFMA16(1, 1, a1, b1); MFMA16(1, 0, a1, b0);                                 \
  PRIO0;                                                                      \
  if ((T)+2 < nt) { VMC(6); } else { VMC(0); }                                \
  BAR; }

template<int EPI>
__global__ __launch_bounds__(512, 2) void k_gemm256(
    const u16* __restrict__ A, const u16* __restrict__ B,
    const float* __restrict__ scale,
    u16* __restrict__ obf, float* __restrict__ of32,
    int K, int NBN, int ldc)
{
    __shared__ __align__(16) u16 lds[65536];   // 128 KiB

    const int tid  = threadIdx.x;
    const int lane = tid & 63;
    const int wave = tid >> 6;          // 0..7
    const int wm   = wave >> 2;         // 0..1
    const int wn   = wave & 3;          // 0..3

    // XCD-aware bijective swizzle (m204)
    const int nwg  = 16 * NBN;
    const int orig = blockIdx.x;
    const int qq   = nwg >> 3, rr = nwg & 7;
    const int xcd  = orig & 7;
    const int swz  = (xcd < rr ? xcd*(qq+1) : rr*(qq+1) + (xcd-rr)*qq) + (orig >> 3);
    const int bm   = swz & 15;          // M blocks = 4096/256 = 16
    const int bn   = swz >> 4;

    // fragment-read per-thread constants (byte offsets)
    const int r    = lane & 15;
    const int sQ   = lane >> 4;         // 0..3
    const int x7   = r & 7;
    const int g0B  = ((sQ ^ x7) * 8) * 2;         // kk=0 granule, bytes
    const int g1B  = (((4 | sQ) ^ x7) * 8) * 2;   // kk=1 granule, bytes
    const int aoffB = (wm*64 + r) * 128;
    const int boffB = (wn*32 + r) * 128;

    const u32 lbase = (u32)(uintptr_t)(__attribute__((address_space(3))) u16*)&lds[0];
    const u32 adA0g0 = lbase + aoffB + g0B;
    const u32 adA0g1 = lbase + aoffB + g1B;
    const u32 adA1g0 = adA0g0 + 65536;
    const u32 adA1g1 = adA0g1 + 65536;
    const u32 adB0g0 = lbase + 32768 + boffB + g0B;
    const u32 adB0g1 = lbase + 32768 + boffB + g1B;
    const u32 adB1g0 = adB0g0 + 65536;
    const u32 adB1g1 = adB0g1 + 65536;

    // stage per-thread constants (inverse swizzle on the global source)
    const int lrow = lane >> 3;                       // 0..7
    const int goff = ((lane & 7) ^ lrow) * 8;         // elems within 64-col row
    const size_t a_sbase = (size_t)(bm*256 + wave*8 + lrow) * K + goff;
    const size_t b_sbase = (size_t)(bn*256 + wave*8 + lrow) * K + goff;

    f32x4 acc[8][4];
#pragma unroll
    for (int m = 0; m < 8; ++m)
#pragma unroll
        for (int n = 0; n < 4; ++n) acc[m][n] = (f32x4){0.f, 0.f, 0.f, 0.f};

    const int nt = K >> 6;              // K/64: 64 (K=4096) or 172 (K=11008), even

    // ---- prologue: tile0 complete -> buf0 [8]; tile1 {Ah0,Bh0,Bh1} -> buf1 [6]
    STAGE_A(0, 0, 0); STAGE_A(0, 1, 0); STAGE_B(0, 0, 0); STAGE_B(0, 1, 0);
    STAGE_A(1, 0, 64); STAGE_B(1, 0, 64); STAGE_B(1, 1, 64);
    VMC(6);                              // tile0's 8 gloads complete per-wave
    BAR;                                 // all waves' tile0 staging complete

    bf16x8 a0[4][2], a1[4][2], b0[2][2], b1[2][2];

    for (int t = 0; t < nt; t += 2) {
        TILE2(0, 1, t);
        TILE2(1, 0, t + 1);
    }

    // ---- epilogue
#pragma unroll
    for (int n = 0; n < 4; ++n) {
        const int col = bn*256 + (n>>1)*128 + wn*32 + (n&1)*16 + r;
        const float sc = scale[col];
#pragma unroll
        for (int m = 0; m < 8; ++m) {
            const int row = bm*256 + (m>>2)*128 + wm*64 + (m&3)*16 + sQ*4;
#pragma unroll
            for (int q = 0; q < 4; ++q) {
                const float v = acc[m][n][q] * sc;
                const size_t idx = (size_t)(row + q) * ldc + col;
                if constexpr (EPI == 0) {
                    obf[idx] = bf16_rn(v);
                } else if constexpr (EPI == 1) {
                    const float g = bf16_to_f(obf[idx]);
                    const float s2 = g / (1.0f + __expf(-g));
                    obf[idx] = bf16_rn(s2 * v);
                } else {
                    of32[idx] = v;
                }
            }
        }
    }
}

extern "C" void kernel_launch(void* const* d_in, const int* in_sizes, int n_in,
                              void* d_out, int out_size, void* d_ws, size_t ws_size,
                              hipStream_t stream) {
    const float* x  = (const float*)d_in[0];
    const int*   gw = (const int*)d_in[1];
    const float* gs = (const float*)d_in[2];
    const int*   uw = (const int*)d_in[3];
    const float* us = (const float*)d_in[4];
    const int*   dw = (const int*)d_in[5];
    const float* ds = (const float*)d_in[6];
    float* out = (float*)d_out;

    const size_t XB = (size_t)NTOK * D_MODEL * 2;   // 33.5 MB  x bf16
    const size_t WB = (size_t)D_FF * D_MODEL * 2;   // 90.2 MB  weight bf16
    const size_t HB = WB;                           // 90.2 MB  g/h bf16
    if (ws_size < XB + WB + HB) return;             // loud failure (poisoned out)

    char* ws = (char*)d_ws;
    u16* xb   = (u16*)ws;
    u16* wb   = (u16*)(ws + XB);
    u16* gbuf = (u16*)(ws + XB + WB);

    const int wn_elems = D_FF * D_MODEL;            // 45,088,768
    const int wgrid = wn_elems / (8 * 256);

    k_cvt_x<<<(NTOK * D_MODEL) / (8 * 256), 256, 0, stream>>>(x, xb);

    // gate: g = bf16( (xb . gw^T) * gs )
    k_cvt_w<<<wgrid, 256, 0, stream>>>(gw, wb, wn_elems);
    k_gemm256<0><<<16 * (D_FF / 256), 512, 0, stream>>>(
        xb, wb, gs, gbuf, nullptr, D_MODEL, D_FF / 256, D_FF);

    // up + fuse: h = bf16( silu(g) * (xb . uw^T) * us )   (in-place into gbuf)
    k_cvt_w<<<wgrid, 256, 0, stream>>>(uw, wb, wn_elems);
    k_gemm256<1><<<16 * (D_FF / 256), 512, 0, stream>>>(
        xb, wb, us, gbuf, nullptr, D_MODEL, D_FF / 256, D_FF);

    // down: out = (h . dw^T) * ds   (fp32)
    k_cvt_w<<<wgrid, 256, 0, stream>>>(dw, wb, wn_elems);
    k_gemm256<2><<<16 * (D_MODEL / 256), 512, 0, stream>>>(
        gbuf, wb, ds, nullptr, out, D_FF, D_MODEL / 256, D_MODEL);
}

// Round 9
// 1125.407 us; speedup vs baseline: 1.3619x; 1.1182x over previous
//
#include <hip/hip_runtime.h>
#include <hip/hip_bf16.h>

#define D_MODEL 4096
#define D_FF    11008
#define NTOK    4096   // 2 * 2048 tokens

typedef unsigned int u32;
typedef unsigned short u16;
using f32x4   = __attribute__((ext_vector_type(4))) float;
using bf16x8  = __attribute__((ext_vector_type(8))) short;
using ushort8 = __attribute__((ext_vector_type(8))) unsigned short;
using int4v   = __attribute__((ext_vector_type(4))) int;
using float4v = __attribute__((ext_vector_type(4))) float;

__device__ __forceinline__ u16 bf16_rn(float f) {
    u32 u = __builtin_bit_cast(u32, f);
    u += 0x7FFFu + ((u >> 16) & 1u);
    return (u16)(u >> 16);
}
__device__ __forceinline__ u16 bf16_from_int(int v) {
    float f = (float)v;   // exact for |v| <= 127
    return (u16)(__builtin_bit_cast(u32, f) >> 16);
}
__device__ __forceinline__ float bf16_to_f(u16 b) {
    u32 u = (u32)b << 16;
    return __builtin_bit_cast(float, u);
}
__device__ __forceinline__ void gload16(const void* g, void* l) {
    __builtin_amdgcn_global_load_lds(
        (const __attribute__((address_space(1))) u32*)g,
        (__attribute__((address_space(3))) u32*)l, 16, 0, 0);
}

// ---------------- x fp32 -> bf16 ----------------
__global__ void k_cvt_x(const float* __restrict__ x, u16* __restrict__ xb) {
    int i = (blockIdx.x * 256 + threadIdx.x) * 8;
    float4v a = *(const float4v*)(x + i);
    float4v b = *(const float4v*)(x + i + 4);
    ushort8 o;
    o[0] = bf16_rn(a[0]); o[1] = bf16_rn(a[1]); o[2] = bf16_rn(a[2]); o[3] = bf16_rn(a[3]);
    o[4] = bf16_rn(b[0]); o[5] = bf16_rn(b[1]); o[6] = bf16_rn(b[2]); o[7] = bf16_rn(b[3]);
    *(ushort8*)(xb + i) = o;
}

// ---------------- weight int32 -> bf16 ----------------
__global__ void k_cvt_w(const int* __restrict__ w, u16* __restrict__ wb, int n) {
    int i = (blockIdx.x * 256 + threadIdx.x) * 8;
    if (i >= n) return;
    int4v a = *(const int4v*)(w + i);
    int4v b = *(const int4v*)(w + i + 4);
    ushort8 o;
    o[0] = bf16_from_int(a[0]); o[1] = bf16_from_int(a[1]);
    o[2] = bf16_from_int(a[2]); o[3] = bf16_from_int(a[3]);
    o[4] = bf16_from_int(b[0]); o[5] = bf16_from_int(b[1]);
    o[6] = bf16_from_int(b[2]); o[7] = bf16_from_int(b[3]);
    *(ushort8*)(wb + i) = o;
}

// =====================================================================
// 256x256 GEMM, 2 phases/K-tile (R8-proven pipeline, untouched).
// B-tile = two independent 128-row halves with separate base pointers:
//   EPI=3 (FUSED gate+up): h0 = gate_w[bn*128..], h1 = up_w[bn*128..]
//          -> acc[m][0..1]=gate, acc[m][2..3]=up for the SAME f-columns;
//          epilogue: h = bf16( silu(g*gs) * (u*us) )   (g stays fp32)
//   EPI=2 (down): h0/h1 = dw[bn*256 + {0,128}..], of32 = acc*scale
//   EPI=0/1: unfused fallback (gate out / up+silu in-place), as R8.
// 8 waves (2Mx4N), BK=64, dbuf 128 KiB LDS, XOR-granule swizzle,
// gload_lds staging (pre-swizzled source), vmcnt(6), setprio.
// =====================================================================

#define DSR(dst, addr, IMM)                                                   \
  asm volatile("ds_read_b128 %0, %1 offset:%c2"                               \
               : "=v"(dst) : "v"(addr), "i"(IMM))

#define READA(AA, BUF, MH) {                                                  \
  DSR(AA[0][0], adA##BUF##g0, (MH)*16384 + 0);                                \
  DSR(AA[0][1], adA##BUF##g1, (MH)*16384 + 0);                                \
  DSR(AA[1][0], adA##BUF##g0, (MH)*16384 + 2048);                             \
  DSR(AA[1][1], adA##BUF##g1, (MH)*16384 + 2048);                             \
  DSR(AA[2][0], adA##BUF##g0, (MH)*16384 + 4096);                             \
  DSR(AA[2][1], adA##BUF##g1, (MH)*16384 + 4096);                             \
  DSR(AA[3][0], adA##BUF##g0, (MH)*16384 + 6144);                             \
  DSR(AA[3][1], adA##BUF##g1, (MH)*16384 + 6144); }

#define READB(BB, BUF, NH) {                                                  \
  DSR(BB[0][0], adB##BUF##g0, (NH)*16384 + 0);                                \
  DSR(BB[0][1], adB##BUF##g1, (NH)*16384 + 0);                                \
  DSR(BB[1][0], adB##BUF##g0, (NH)*16384 + 2048);                             \
  DSR(BB[1][1], adB##BUF##g1, (NH)*16384 + 2048); }

#define MFMA16(MH, NH, AA, BB)                                                \
  _Pragma("unroll") for (int mm = 0; mm < 4; ++mm)                            \
  _Pragma("unroll") for (int nn = 0; nn < 2; ++nn)                            \
  _Pragma("unroll") for (int kk = 0; kk < 2; ++kk)                            \
    acc[(MH)*4+mm][(NH)*2+nn] = __builtin_amdgcn_mfma_f32_16x16x32_bf16(      \
        AA[mm][kk], BB[nn][kk], acc[(MH)*4+mm][(NH)*2+nn], 0, 0, 0);

// LDS element offsets for staging (ushort units)
#define REGA(BUF, H) ((BUF)*32768 + (H)*8192)
#define REGB(BUF, H) ((BUF)*32768 + 16384 + (H)*8192)

#define STAGE_A(BUF, MH, K0) {                                                \
  const u16* _s = A + a_sbase + (size_t)(MH)*128*K + (K0);                    \
  gload16(_s,                &lds[REGA(BUF, MH) + wave*512]);                 \
  gload16(_s + (size_t)64*K, &lds[REGA(BUF, MH) + (8+wave)*512]); }

// NH is a literal 0/1 at every use -> base select folds at compile time
#define STAGE_B(BUF, NH, K0) {                                                \
  const u16* _s = ((NH) ? b1base : b0base) + (K0);                            \
  gload16(_s,                &lds[REGB(BUF, NH) + wave*512]);                 \
  gload16(_s + (size_t)64*K, &lds[REGB(BUF, NH) + (8+wave)*512]); }

#define BAR   __builtin_amdgcn_s_barrier()
#define SB0   __builtin_amdgcn_sched_barrier(0)
#define PRIO1 __builtin_amdgcn_s_setprio(1)
#define PRIO0 __builtin_amdgcn_s_setprio(0)
#define VMC(N)  asm volatile("s_waitcnt vmcnt(" #N ")" ::: "memory")
#define LGKM(N) asm volatile("s_waitcnt lgkmcnt(" #N ")" ::: "memory")

#define TILE2(CUR, NXT, T) {                                                  \
  /* Ph1: read a0,b0,b1 of CUR; stage A(T+1)h1 -> NXT; MFMA Q1,Q2 */          \
  READA(a0, CUR, 0); READB(b0, CUR, 0); READB(b1, CUR, 1);                    \
  if ((T)+1 < nt) STAGE_A(NXT, 1, ((T)+1) << 6);                              \
  BAR; LGKM(0); SB0; PRIO1;                                                   \
  MFMA16(0, 0, a0, b0); MFMA16(0, 1, a0, b1);                                 \
  PRIO0; BAR;                                                                 \
  /* Ph2: read a1 of CUR; stage A(T+2)h0,B(T+2)h0,B(T+2)h1 -> CUR */          \
  READA(a1, CUR, 1);                                                          \
  if ((T)+2 < nt) { STAGE_A(CUR, 0, ((T)+2) << 6);                            \
                    STAGE_B(CUR, 0, ((T)+2) << 6);                            \
                    STAGE_B(CUR, 1, ((T)+2) << 6); }                          \
  BAR; LGKM(0); SB0; PRIO1;                                                   \
  MFMA16(1, 1, a1, b1); MFMA16(1, 0, a1, b0);                                 \
  PRIO0;                                                                      \
  if ((T)+2 < nt) { VMC(6); } else { VMC(0); }                                \
  BAR; }

template<int EPI>
__global__ __launch_bounds__(512, 2) void k_gemm256(
    const u16* __restrict__ A,
    const u16* __restrict__ B0, const u16* __restrict__ B1,
    const float* __restrict__ sc0, const float* __restrict__ sc1,
    u16* __restrict__ obf, float* __restrict__ of32,
    int K, int NBN, int ldc)
{
    __shared__ __align__(16) u16 lds[65536];   // 128 KiB

    constexpr int S0 = (EPI == 3) ? 128 : 256;   // B row-block stride per bn
    constexpr int H1 = (EPI == 3) ? 0   : 128;   // row offset of half1 in B1

    const int tid  = threadIdx.x;
    const int lane = tid & 63;
    const int wave = tid >> 6;          // 0..7
    const int wm   = wave >> 2;         // 0..1
    const int wn   = wave & 3;          // 0..3

    // XCD-aware bijective swizzle (m204)
    const int nwg  = 16 * NBN;
    const int orig = blockIdx.x;
    const int qq   = nwg >> 3, rr = nwg & 7;
    const int xcd  = orig & 7;
    const int swz  = (xcd < rr ? xcd*(qq+1) : rr*(qq+1) + (xcd-rr)*qq) + (orig >> 3);
    const int bm   = swz & 15;          // M blocks = 4096/256 = 16
    const int bn   = swz >> 4;

    // fragment-read per-thread constants (byte offsets)
    const int r    = lane & 15;
    const int sQ   = lane >> 4;         // 0..3
    const int x7   = r & 7;
    const int g0B  = ((sQ ^ x7) * 8) * 2;         // kk=0 granule, bytes
    const int g1B  = (((4 | sQ) ^ x7) * 8) * 2;   // kk=1 granule, bytes
    const int aoffB = (wm*64 + r) * 128;
    const int boffB = (wn*32 + r) * 128;

    const u32 lbase = (u32)(uintptr_t)(__attribute__((address_space(3))) u16*)&lds[0];
    const u32 adA0g0 = lbase + aoffB + g0B;
    const u32 adA0g1 = lbase + aoffB + g1B;
    const u32 adA1g0 = adA0g0 + 65536;
    const u32 adA1g1 = adA0g1 + 65536;
    const u32 adB0g0 = lbase + 32768 + boffB + g0B;
    const u32 adB0g1 = lbase + 32768 + boffB + g1B;
    const u32 adB1g0 = adB0g0 + 65536;
    const u32 adB1g1 = adB0g1 + 65536;

    // stage per-thread constants (inverse swizzle on the global source)
    const int lrow = lane >> 3;                       // 0..7
    const int goff = ((lane & 7) ^ lrow) * 8;         // elems within 64-col row
    const size_t a_sbase = (size_t)(bm*256 + wave*8 + lrow) * K + goff;
    const u16* b0base = B0 + (size_t)(bn*S0 +      wave*8 + lrow) * K + goff;
    const u16* b1base = B1 + (size_t)(bn*S0 + H1 + wave*8 + lrow) * K + goff;

    f32x4 acc[8][4];
#pragma unroll
    for (int m = 0; m < 8; ++m)
#pragma unroll
        for (int n = 0; n < 4; ++n) acc[m][n] = (f32x4){0.f, 0.f, 0.f, 0.f};

    const int nt = K >> 6;              // K/64: 64 (K=4096) or 172 (K=11008), even

    // ---- prologue: tile0 complete -> buf0 [8]; tile1 {Ah0,Bh0,Bh1} -> buf1 [6]
    STAGE_A(0, 0, 0); STAGE_A(0, 1, 0); STAGE_B(0, 0, 0); STAGE_B(0, 1, 0);
    STAGE_A(1, 0, 64); STAGE_B(1, 0, 64); STAGE_B(1, 1, 64);
    VMC(6);                              // tile0's 8 gloads complete per-wave
    BAR;                                 // all waves' tile0 staging complete

    bf16x8 a0[4][2], a1[4][2], b0[2][2], b1[2][2];

    for (int t = 0; t < nt; t += 2) {
        TILE2(0, 1, t);
        TILE2(1, 0, t + 1);
    }

    // ---- epilogue
    if constexpr (EPI == 3) {
        // fused gate+up: acc[m][n] (gate) pairs with acc[m][n+2] (up), same f
#pragma unroll
        for (int n = 0; n < 2; ++n) {
            const int f = bn*128 + wn*32 + n*16 + r;
            const float gsc = sc0[f];
            const float usc = sc1[f];
#pragma unroll
            for (int m = 0; m < 8; ++m) {
                const int row = bm*256 + (m>>2)*128 + wm*64 + (m&3)*16 + sQ*4;
#pragma unroll
                for (int q = 0; q < 4; ++q) {
                    const float g = acc[m][n][q] * gsc;
                    const float u = acc[m][n+2][q] * usc;
                    const float s2 = g / (1.0f + __expf(-g));
                    obf[(size_t)(row + q) * ldc + f] = bf16_rn(s2 * u);
                }
            }
        }
    } else {
#pragma unroll
        for (int n = 0; n < 4; ++n) {
            const int col = bn*256 + (n>>1)*128 + wn*32 + (n&1)*16 + r;
            const float sc = sc0[col];
#pragma unroll
            for (int m = 0; m < 8; ++m) {
                const int row = bm*256 + (m>>2)*128 + wm*64 + (m&3)*16 + sQ*4;
#pragma unroll
                for (int q = 0; q < 4; ++q) {
                    const float v = acc[m][n][q] * sc;
                    const size_t idx = (size_t)(row + q) * ldc + col;
                    if constexpr (EPI == 0) {
                        obf[idx] = bf16_rn(v);
                    } else if constexpr (EPI == 1) {
                        const float g = bf16_to_f(obf[idx]);
                        const float s2 = g / (1.0f + __expf(-g));
                        obf[idx] = bf16_rn(s2 * v);
                    } else {
                        of32[idx] = v;
                    }
                }
            }
        }
    }
}

extern "C" void kernel_launch(void* const* d_in, const int* in_sizes, int n_in,
                              void* d_out, int out_size, void* d_ws, size_t ws_size,
                              hipStream_t stream) {
    const float* x  = (const float*)d_in[0];
    const int*   gw = (const int*)d_in[1];
    const float* gs = (const float*)d_in[2];
    const int*   uw = (const int*)d_in[3];
    const float* us = (const float*)d_in[4];
    const int*   dw = (const int*)d_in[5];
    const float* ds = (const float*)d_in[6];
    float* out = (float*)d_out;

    const size_t XB = (size_t)NTOK * D_MODEL * 2;   // 33.5 MB  x bf16
    const size_t WB = (size_t)D_FF * D_MODEL * 2;   // 90.2 MB  weight bf16
    const size_t HB = (size_t)NTOK * D_FF * 2;      // 90.2 MB  h bf16

    char* ws = (char*)d_ws;
    const int wn_elems = D_FF * D_MODEL;            // 45,088,768
    const int wgrid = wn_elems / (8 * 256);

    if (ws_size >= XB + 2 * WB + HB) {
        // ---- Plan A: fused gate+up GEMM ----
        u16* xb  = (u16*)ws;
        u16* wbG = (u16*)(ws + XB);
        u16* wbU = (u16*)(ws + XB + WB);
        u16* hb  = (u16*)(ws + XB + 2 * WB);

        k_cvt_x<<<(NTOK * D_MODEL) / (8 * 256), 256, 0, stream>>>(x, xb);
        k_cvt_w<<<wgrid, 256, 0, stream>>>(gw, wbG, wn_elems);
        k_cvt_w<<<wgrid, 256, 0, stream>>>(uw, wbU, wn_elems);

        // fused: h = bf16( silu((xb.gw^T)*gs) * (xb.uw^T)*us )
        k_gemm256<3><<<16 * (D_FF / 128), 512, 0, stream>>>(
            xb, wbG, wbU, gs, us, hb, nullptr, D_MODEL, D_FF / 128, D_FF);

        // down: out = (h . dw^T) * ds
        k_cvt_w<<<wgrid, 256, 0, stream>>>(dw, wbG, wn_elems);
        k_gemm256<2><<<16 * (D_MODEL / 256), 512, 0, stream>>>(
            hb, wbG, wbG, ds, nullptr, nullptr, out, D_FF, D_MODEL / 256, D_MODEL);
    } else if (ws_size >= XB + WB + HB) {
        // ---- Plan B: unfused (R8-proven) ----
        u16* xb   = (u16*)ws;
        u16* wb   = (u16*)(ws + XB);
        u16* gbuf = (u16*)(ws + XB + WB);

        k_cvt_x<<<(NTOK * D_MODEL) / (8 * 256), 256, 0, stream>>>(x, xb);

        k_cvt_w<<<wgrid, 256, 0, stream>>>(gw, wb, wn_elems);
        k_gemm256<0><<<16 * (D_FF / 256), 512, 0, stream>>>(
            xb, wb, wb, gs, nullptr, gbuf, nullptr, D_MODEL, D_FF / 256, D_FF);

        k_cvt_w<<<wgrid, 256, 0, stream>>>(uw, wb, wn_elems);
        k_gemm256<1><<<16 * (D_FF / 256), 512, 0, stream>>>(
            xb, wb, wb, us, nullptr, gbuf, nullptr, D_MODEL, D_FF / 256, D_FF);

        k_cvt_w<<<wgrid, 256, 0, stream>>>(dw, wb, wn_elems);
        k_gemm256<2><<<16 * (D_MODEL / 256), 512, 0, stream>>>(
            gbuf, wb, wb, ds, nullptr, nullptr, out, D_FF, D_MODEL / 256, D_MODEL);
    }
    // else: insufficient workspace -> loud failure (poisoned out)
}

// Round 10
// 1116.034 us; speedup vs baseline: 1.3733x; 1.0084x over previous
//
#include <hip/hip_runtime.h>
#include <hip/hip_bf16.h>

#define D_MODEL 4096
#define D_FF    11008
#define NTOK    4096   // 2 * 2048 tokens

typedef unsigned int u32;
typedef unsigned short u16;
using f32x4   = __attribute__((ext_vector_type(4))) float;
using bf16x8  = __attribute__((ext_vector_type(8))) short;
using ushort8 = __attribute__((ext_vector_type(8))) unsigned short;
using int4v   = __attribute__((ext_vector_type(4))) int;
using float4v = __attribute__((ext_vector_type(4))) float;

__device__ __forceinline__ u16 bf16_rn(float f) {
    u32 u = __builtin_bit_cast(u32, f);
    u += 0x7FFFu + ((u >> 16) & 1u);
    return (u16)(u >> 16);
}
__device__ __forceinline__ u16 bf16_from_int(int v) {
    float f = (float)v;   // exact for |v| <= 127
    return (u16)(__builtin_bit_cast(u32, f) >> 16);
}
__device__ __forceinline__ float bf16_to_f(u16 b) {
    u32 u = (u32)b << 16;
    return __builtin_bit_cast(float, u);
}
__device__ __forceinline__ void gload16(const void* g, void* l) {
    __builtin_amdgcn_global_load_lds(
        (const __attribute__((address_space(1))) u32*)g,
        (__attribute__((address_space(3))) u32*)l, 16, 0, 0);
}

// ---------------- x fp32 -> bf16 ----------------
__global__ void k_cvt_x(const float* __restrict__ x, u16* __restrict__ xb) {
    int i = (blockIdx.x * 256 + threadIdx.x) * 8;
    float4v a = *(const float4v*)(x + i);
    float4v b = *(const float4v*)(x + i + 4);
    ushort8 o;
    o[0] = bf16_rn(a[0]); o[1] = bf16_rn(a[1]); o[2] = bf16_rn(a[2]); o[3] = bf16_rn(a[3]);
    o[4] = bf16_rn(b[0]); o[5] = bf16_rn(b[1]); o[6] = bf16_rn(b[2]); o[7] = bf16_rn(b[3]);
    *(ushort8*)(xb + i) = o;
}

// ---------------- weight int32 -> bf16 ----------------
__global__ void k_cvt_w(const int* __restrict__ w, u16* __restrict__ wb, int n) {
    int i = (blockIdx.x * 256 + threadIdx.x) * 8;
    if (i >= n) return;
    int4v a = *(const int4v*)(w + i);
    int4v b = *(const int4v*)(w + i + 4);
    ushort8 o;
    o[0] = bf16_from_int(a[0]); o[1] = bf16_from_int(a[1]);
    o[2] = bf16_from_int(a[2]); o[3] = bf16_from_int(a[3]);
    o[4] = bf16_from_int(b[0]); o[5] = bf16_from_int(b[1]);
    o[6] = bf16_from_int(b[2]); o[7] = bf16_from_int(b[3]);
    *(ushort8*)(wb + i) = o;
}

// =====================================================================
// 256x256 GEMM, 2 phases/K-tile (R8-proven pipeline, untouched).
// R10 change: block-index decomposition bm = swz/NBN, bn = swz%NBN
// (bn FAST within an XCD's contiguous chunk) -> the ~32 concurrent
// blocks on one XCD share a single 2MB A-panel (L2-resident) instead
// of thrashing 16 panels through 4MB L2. Cuts A re-fetch from HBM and
// the vmcnt(6) latency exposure.
// B-tile = two independent 128-row halves with separate base pointers:
//   EPI=3 (FUSED gate+up): h0 = gate_w[bn*128..], h1 = up_w[bn*128..]
//          -> acc[m][0..1]=gate, acc[m][2..3]=up for the SAME f-cols;
//          epilogue: h = bf16( silu(g*gs) * (u*us) )   (g stays fp32)
//   EPI=2 (down): h0/h1 = dw[bn*256 + {0,128}..], of32 = acc*scale
//   EPI=0/1: unfused fallback.
// 8 waves (2Mx4N), BK=64, dbuf 128 KiB LDS, XOR-granule swizzle,
// gload_lds staging (pre-swizzled source), vmcnt(6), setprio.
// =====================================================================

#define DSR(dst, addr, IMM)                                                   \
  asm volatile("ds_read_b128 %0, %1 offset:%c2"                               \
               : "=v"(dst) : "v"(addr), "i"(IMM))

#define READA(AA, BUF, MH) {                                                  \
  DSR(AA[0][0], adA##BUF##g0, (MH)*16384 + 0);                                \
  DSR(AA[0][1], adA##BUF##g1, (MH)*16384 + 0);                                \
  DSR(AA[1][0], adA##BUF##g0, (MH)*16384 + 2048);                             \
  DSR(AA[1][1], adA##BUF##g1, (MH)*16384 + 2048);                             \
  DSR(AA[2][0], adA##BUF##g0, (MH)*16384 + 4096);                             \
  DSR(AA[2][1], adA##BUF##g1, (MH)*16384 + 4096);                             \
  DSR(AA[3][0], adA##BUF##g0, (MH)*16384 + 6144);                             \
  DSR(AA[3][1], adA##BUF##g1, (MH)*16384 + 6144); }

#define READB(BB, BUF, NH) {                                                  \
  DSR(BB[0][0], adB##BUF##g0, (NH)*16384 + 0);                                \
  DSR(BB[0][1], adB##BUF##g1, (NH)*16384 + 0);                                \
  DSR(BB[1][0], adB##BUF##g0, (NH)*16384 + 2048);                             \
  DSR(BB[1][1], adB##BUF##g1, (NH)*16384 + 2048); }

#define MFMA16(MH, NH, AA, BB)                                                \
  _Pragma("unroll") for (int mm = 0; mm < 4; ++mm)                            \
  _Pragma("unroll") for (int nn = 0; nn < 2; ++nn)                            \
  _Pragma("unroll") for (int kk = 0; kk < 2; ++kk)                            \
    acc[(MH)*4+mm][(NH)*2+nn] = __builtin_amdgcn_mfma_f32_16x16x32_bf16(      \
        AA[mm][kk], BB[nn][kk], acc[(MH)*4+mm][(NH)*2+nn], 0, 0, 0);

// LDS element offsets for staging (ushort units)
#define REGA(BUF, H) ((BUF)*32768 + (H)*8192)
#define REGB(BUF, H) ((BUF)*32768 + 16384 + (H)*8192)

#define STAGE_A(BUF, MH, K0) {                                                \
  const u16* _s = A + a_sbase + (size_t)(MH)*128*K + (K0);                    \
  gload16(_s,                &lds[REGA(BUF, MH) + wave*512]);                 \
  gload16(_s + (size_t)64*K, &lds[REGA(BUF, MH) + (8+wave)*512]); }

// NH is a literal 0/1 at every use -> base select folds at compile time
#define STAGE_B(BUF, NH, K0) {                                                \
  const u16* _s = ((NH) ? b1base : b0base) + (K0);                            \
  gload16(_s,                &lds[REGB(BUF, NH) + wave*512]);                 \
  gload16(_s + (size_t)64*K, &lds[REGB(BUF, NH) + (8+wave)*512]); }

#define BAR   __builtin_amdgcn_s_barrier()
#define SB0   __builtin_amdgcn_sched_barrier(0)
#define PRIO1 __builtin_amdgcn_s_setprio(1)
#define PRIO0 __builtin_amdgcn_s_setprio(0)
#define VMC(N)  asm volatile("s_waitcnt vmcnt(" #N ")" ::: "memory")
#define LGKM(N) asm volatile("s_waitcnt lgkmcnt(" #N ")" ::: "memory")

#define TILE2(CUR, NXT, T) {                                                  \
  /* Ph1: read a0,b0,b1 of CUR; stage A(T+1)h1 -> NXT; MFMA Q1,Q2 */          \
  READA(a0, CUR, 0); READB(b0, CUR, 0); READB(b1, CUR, 1);                    \
  if ((T)+1 < nt) STAGE_A(NXT, 1, ((T)+1) << 6);                              \
  BAR; LGKM(0); SB0; PRIO1;                                                   \
  MFMA16(0, 0, a0, b0); MFMA16(0, 1, a0, b1);                                 \
  PRIO0; BAR;                                                                 \
  /* Ph2: read a1 of CUR; stage A(T+2)h0,B(T+2)h0,B(T+2)h1 -> CUR */          \
  READA(a1, CUR, 1);                                                          \
  if ((T)+2 < nt) { STAGE_A(CUR, 0, ((T)+2) << 6);                            \
                    STAGE_B(CUR, 0, ((T)+2) << 6);                            \
                    STAGE_B(CUR, 1, ((T)+2) << 6); }                          \
  BAR; LGKM(0); SB0; PRIO1;                                                   \
  MFMA16(1, 1, a1, b1); MFMA16(1, 0, a1, b0);                                 \
  PRIO0;                                                                      \
  if ((T)+2 < nt) { VMC(6); } else { VMC(0); }                                \
  BAR; }

template<int EPI>
__global__ __launch_bounds__(512, 2) void k_gemm256(
    const u16* __restrict__ A,
    const u16* __restrict__ B0, const u16* __restrict__ B1,
    const float* __restrict__ sc0, const float* __restrict__ sc1,
    u16* __restrict__ obf, float* __restrict__ of32,
    int K, int NBN, int ldc)
{
    __shared__ __align__(16) u16 lds[65536];   // 128 KiB

    constexpr int S0 = (EPI == 3) ? 128 : 256;   // B row-block stride per bn
    constexpr int H1 = (EPI == 3) ? 0   : 128;   // row offset of half1 in B1

    const int tid  = threadIdx.x;
    const int lane = tid & 63;
    const int wave = tid >> 6;          // 0..7
    const int wm   = wave >> 2;         // 0..1
    const int wn   = wave & 3;          // 0..3

    // XCD-aware bijective swizzle (m204); R10: bn FAST within XCD chunk
    const int nwg  = 16 * NBN;
    const int orig = blockIdx.x;
    const int qq   = nwg >> 3, rr = nwg & 7;
    const int xcd  = orig & 7;
    const int swz  = (xcd < rr ? xcd*(qq+1) : rr*(qq+1) + (xcd-rr)*qq) + (orig >> 3);
    const int bm   = swz / NBN;         // SLOW: one A-panel per ~NBN blocks
    const int bn   = swz % NBN;         // FAST: B streams, A L2-resident

    // fragment-read per-thread constants (byte offsets)
    const int r    = lane & 15;
    const int sQ   = lane >> 4;         // 0..3
    const int x7   = r & 7;
    const int g0B  = ((sQ ^ x7) * 8) * 2;         // kk=0 granule, bytes
    const int g1B  = (((4 | sQ) ^ x7) * 8) * 2;   // kk=1 granule, bytes
    const int aoffB = (wm*64 + r) * 128;
    const int boffB = (wn*32 + r) * 128;

    const u32 lbase = (u32)(uintptr_t)(__attribute__((address_space(3))) u16*)&lds[0];
    const u32 adA0g0 = lbase + aoffB + g0B;
    const u32 adA0g1 = lbase + aoffB + g1B;
    const u32 adA1g0 = adA0g0 + 65536;
    const u32 adA1g1 = adA0g1 + 65536;
    const u32 adB0g0 = lbase + 32768 + boffB + g0B;
    const u32 adB0g1 = lbase + 32768 + boffB + g1B;
    const u32 adB1g0 = adB0g0 + 65536;
    const u32 adB1g1 = adB0g1 + 65536;

    // stage per-thread constants (inverse swizzle on the global source)
    const int lrow = lane >> 3;                       // 0..7
    const int goff = ((lane & 7) ^ lrow) * 8;         // elems within 64-col row
    const size_t a_sbase = (size_t)(bm*256 + wave*8 + lrow) * K + goff;
    const u16* b0base = B0 + (size_t)(bn*S0 +      wave*8 + lrow) * K + goff;
    const u16* b1base = B1 + (size_t)(bn*S0 + H1 + wave*8 + lrow) * K + goff;

    f32x4 acc[8][4];
#pragma unroll
    for (int m = 0; m < 8; ++m)
#pragma unroll
        for (int n = 0; n < 4; ++n) acc[m][n] = (f32x4){0.f, 0.f, 0.f, 0.f};

    const int nt = K >> 6;              // K/64: 64 (K=4096) or 172 (K=11008), even

    // ---- prologue: tile0 complete -> buf0 [8]; tile1 {Ah0,Bh0,Bh1} -> buf1 [6]
    STAGE_A(0, 0, 0); STAGE_A(0, 1, 0); STAGE_B(0, 0, 0); STAGE_B(0, 1, 0);
    STAGE_A(1, 0, 64); STAGE_B(1, 0, 64); STAGE_B(1, 1, 64);
    VMC(6);                              // tile0's 8 gloads complete per-wave
    BAR;                                 // all waves' tile0 staging complete

    bf16x8 a0[4][2], a1[4][2], b0[2][2], b1[2][2];

    for (int t = 0; t < nt; t += 2) {
        TILE2(0, 1, t);
        TILE2(1, 0, t + 1);
    }

    // ---- epilogue
    if constexpr (EPI == 3) {
        // fused gate+up: acc[m][n] (gate) pairs with acc[m][n+2] (up), same f
#pragma unroll
        for (int n = 0; n < 2; ++n) {
            const int f = bn*128 + wn*32 + n*16 + r;
            const float gsc = sc0[f];
            const float usc = sc1[f];
#pragma unroll
            for (int m = 0; m < 8; ++m) {
                const int row = bm*256 + (m>>2)*128 + wm*64 + (m&3)*16 + sQ*4;
#pragma unroll
                for (int q = 0; q < 4; ++q) {
                    const float g = acc[m][n][q] * gsc;
                    const float u = acc[m][n+2][q] * usc;
                    const float s2 = g / (1.0f + __expf(-g));
                    obf[(size_t)(row + q) * ldc + f] = bf16_rn(s2 * u);
                }
            }
        }
    } else {
#pragma unroll
        for (int n = 0; n < 4; ++n) {
            const int col = bn*256 + (n>>1)*128 + wn*32 + (n&1)*16 + r;
            const float sc = sc0[col];
#pragma unroll
            for (int m = 0; m < 8; ++m) {
                const int row = bm*256 + (m>>2)*128 + wm*64 + (m&3)*16 + sQ*4;
#pragma unroll
                for (int q = 0; q < 4; ++q) {
                    const float v = acc[m][n][q] * sc;
                    const size_t idx = (size_t)(row + q) * ldc + col;
                    if constexpr (EPI == 0) {
                        obf[idx] = bf16_rn(v);
                    } else if constexpr (EPI == 1) {
                        const float g = bf16_to_f(obf[idx]);
                        const float s2 = g / (1.0f + __expf(-g));
                        obf[idx] = bf16_rn(s2 * v);
                    } else {
                        of32[idx] = v;
                    }
                }
            }
        }
    }
}

extern "C" void kernel_launch(void* const* d_in, const int* in_sizes, int n_in,
                              void* d_out, int out_size, void* d_ws, size_t ws_size,
                              hipStream_t stream) {
    const float* x  = (const float*)d_in[0];
    const int*   gw = (const int*)d_in[1];
    const float* gs = (const float*)d_in[2];
    const int*   uw = (const int*)d_in[3];
    const float* us = (const float*)d_in[4];
    const int*   dw = (const int*)d_in[5];
    const float* ds = (const float*)d_in[6];
    float* out = (float*)d_out;

    const size_t XB = (size_t)NTOK * D_MODEL * 2;   // 33.5 MB  x bf16
    const size_t WB = (size_t)D_FF * D_MODEL * 2;   // 90.2 MB  weight bf16
    const size_t HB = (size_t)NTOK * D_FF * 2;      // 90.2 MB  h bf16

    char* ws = (char*)d_ws;
    const int wn_elems = D_FF * D_MODEL;            // 45,088,768
    const int wgrid = wn_elems / (8 * 256);

    if (ws_size >= XB + 2 * WB + HB) {
        // ---- Plan A: fused gate+up GEMM ----
        u16* xb  = (u16*)ws;
        u16* wbG = (u16*)(ws + XB);
        u16* wbU = (u16*)(ws + XB + WB);
        u16* hb  = (u16*)(ws + XB + 2 * WB);

        k_cvt_x<<<(NTOK * D_MODEL) / (8 * 256), 256, 0, stream>>>(x, xb);
        k_cvt_w<<<wgrid, 256, 0, stream>>>(gw, wbG, wn_elems);
        k_cvt_w<<<wgrid, 256, 0, stream>>>(uw, wbU, wn_elems);

        // fused: h = bf16( silu((xb.gw^T)*gs) * (xb.uw^T)*us )
        k_gemm256<3><<<16 * (D_FF / 128), 512, 0, stream>>>(
            xb, wbG, wbU, gs, us, hb, nullptr, D_MODEL, D_FF / 128, D_FF);

        // down: out = (h . dw^T) * ds
        k_cvt_w<<<wgrid, 256, 0, stream>>>(dw, wbG, wn_elems);
        k_gemm256<2><<<16 * (D_MODEL / 256), 512, 0, stream>>>(
            hb, wbG, wbG, ds, nullptr, nullptr, out, D_FF, D_MODEL / 256, D_MODEL);
    } else if (ws_size >= XB + WB + HB) {
        // ---- Plan B: unfused (R8-proven) ----
        u16* xb   = (u16*)ws;
        u16* wb   = (u16*)(ws + XB);
        u16* gbuf = (u16*)(ws + XB + WB);

        k_cvt_x<<<(NTOK * D_MODEL) / (8 * 256), 256, 0, stream>>>(x, xb);

        k_cvt_w<<<wgrid, 256, 0, stream>>>(gw, wb, wn_elems);
        k_gemm256<0><<<16 * (D_FF / 256), 512, 0, stream>>>(
            xb, wb, wb, gs, nullptr, gbuf, nullptr, D_MODEL, D_FF / 256, D_FF);

        k_cvt_w<<<wgrid, 256, 0, stream>>>(uw, wb, wn_elems);
        k_gemm256<1><<<16 * (D_FF / 256), 512, 0, stream>>>(
            xb, wb, wb, us, nullptr, gbuf, nullptr, D_MODEL, D_FF / 256, D_FF);

        k_cvt_w<<<wgrid, 256, 0, stream>>>(dw, wb, wn_elems);
        k_gemm256<2><<<16 * (D_MODEL / 256), 512, 0, stream>>>(
            gbuf, wb, wb, ds, nullptr, nullptr, out, D_FF, D_MODEL / 256, D_MODEL);
    }
    // else: insufficient workspace -> loud failure (poisoned out)
}